// Round 7
// baseline (327.499 us; speedup 1.0000x reference)
//
#include <hip/hip_runtime.h>
#include <hip/hip_bf16.h>
#include <math.h>

// ---------------------------------------------------------------------------
// GATGNN global attention:  softmax_seg( MLP([x|glbl]) )  on MI355X (gfx950)
// R7: 256x128 tile (bytes/MFMA 256->192), 256 thr (2x2 waves, 128x64/wave),
//     BK=32, 48KB LDS, 2 blocks/CU (VGPR-capped). Proven 2-barrier loop.
// ---------------------------------------------------------------------------

#define NSEG 1024

typedef __attribute__((ext_vector_type(8))) short short8;
typedef __attribute__((ext_vector_type(4))) float f32x4;

__device__ __forceinline__ unsigned short f2bf(float f) {
  __hip_bfloat16 h = __float2bfloat16(f);
  return *reinterpret_cast<unsigned short*>(&h);
}
__device__ __forceinline__ float softplus_fast(float z) {
  float t = __expf(-fabsf(z));
  return fmaxf(z, 0.f) + __logf(1.f + t);
}
__device__ __forceinline__ void gll16(const unsigned short* g, unsigned short* l) {
  __builtin_amdgcn_global_load_lds(
      (const __attribute__((address_space(1))) void*)g,
      (__attribute__((address_space(3))) void*)l, 16, 0, 0);
}
// m204 bijective XCD-chunked swizzle: each XCD owns a contiguous L-range.
__device__ __forceinline__ int xcd_swz(int bid, int nwg) {
  int q = nwg >> 3, r = nwg & 7, x = bid & 7, i = bid >> 3;
  return (x < r ? x * (q + 1) : r * (q + 1) + (x - r) * q) + i;
}

// ---------------------------------------------------------------------------
// prep: W0 [620,512] -> W0T bf16 [512,640] (K-pad 0), W1 -> W1T [512,512],
//       zero logits.
// ---------------------------------------------------------------------------
__global__ __launch_bounds__(256) void prep(const float* __restrict__ W0,
                                            const float* __restrict__ W1,
                                            unsigned short* __restrict__ W0T,
                                            unsigned short* __restrict__ W1T,
                                            float* __restrict__ logits, int Mp) {
  int t = blockIdx.x * 256 + threadIdx.x;
  if (t < 512 * 640) {
    int n = t / 640, k = t % 640;
    W0T[t] = f2bf(k < 620 ? W0[(size_t)k * 512 + n] : 0.f);
    return;
  }
  t -= 512 * 640;
  if (t < 512 * 512) {
    int n = t / 512, k = t % 512;
    W1T[t] = f2bf(W1[(size_t)k * 512 + n]);
    return;
  }
  t -= 512 * 512;
  if (t < Mp) logits[t] = 0.f;
}

// ---------------------------------------------------------------------------
// pack: x [N,512] f32 -> X16 [Mp,512] bf16 ; gx [N,108] f32 -> G16 [Mp,128]
// bf16 (cols 108..127 zero). Pad rows (>=N) zeroed. 16B stores.
// ---------------------------------------------------------------------------
__global__ __launch_bounds__(256) void pack(const float* __restrict__ x,
                                            const float* __restrict__ gx,
                                            unsigned short* __restrict__ X16,
                                            unsigned short* __restrict__ G16,
                                            int N, int Mp) {
  int t = blockIdx.x * 256 + threadIdx.x;
  union { unsigned short u[8]; uint4 q; } v;
  if (t < Mp * 64) {
    int row = t >> 6, c = t & 63;
    if (row >= N) {
#pragma unroll
      for (int j = 0; j < 8; ++j) v.u[j] = 0;
    } else {
      const float4* p = (const float4*)(x + (size_t)row * 512 + c * 8);
      float4 a = p[0], b = p[1];
      v.u[0] = f2bf(a.x); v.u[1] = f2bf(a.y); v.u[2] = f2bf(a.z); v.u[3] = f2bf(a.w);
      v.u[4] = f2bf(b.x); v.u[5] = f2bf(b.y); v.u[6] = f2bf(b.z); v.u[7] = f2bf(b.w);
    }
    *reinterpret_cast<uint4*>(X16 + (size_t)row * 512 + c * 8) = v.q;
    return;
  }
  t -= Mp * 64;
  if (t < Mp * 16) {
    int row = t >> 4, c = t & 15;
#pragma unroll
    for (int j = 0; j < 8; ++j) {
      int col = c * 8 + j;
      v.u[j] = (row < N && col < 108) ? f2bf(gx[(size_t)row * 108 + col]) : 0;
    }
    *reinterpret_cast<uint4*>(G16 + (size_t)row * 128 + c * 8) = v.q;
  }
}

// ---------------------------------------------------------------------------
// GEMM: Z[M,512] = A[M,K] * WT[512,K]^T + bias; 256x128 block tile, BK=32,
// 4 waves (2x2), 128x64 per wave, mfma(w,a) (swapped) -> thread holds 4
// consecutive output columns. Both panels via global_load_lds, pre-swizzled
// source (chunk c of local row r -> slot c^((r>>1)&3), conflict-free
// ds_read_b128). LDS 48KB, 2 blocks/CU (VGPR <= 256 via launch_bounds).
//  SPLITA: A = [A1 (stride 512) | A2 (stride 128)], boundary at k=512.
//  FUSE=false: C = bf16(softplus(Z))                       (layer 0 -> H0)
//  FUSE=true : logits[m] += sum_n softplus(Z[m,n])*W2[n]   (layers 1+2)
// ---------------------------------------------------------------------------
template <int K, bool SPLITA, bool FUSE>
__global__ __launch_bounds__(256, 2) void gemm_bf16(const unsigned short* __restrict__ A1,
                                                    const unsigned short* __restrict__ A2,
                                                    const unsigned short* __restrict__ WT,
                                                    const float* __restrict__ bias,
                                                    unsigned short* __restrict__ C,
                                                    const float* __restrict__ W2,
                                                    float* __restrict__ logits, int nwg) {
  constexpr int KT = K / 32;
  __shared__ unsigned short As[2][256 * 32];   // 16KB each
  __shared__ unsigned short Ws[2][128 * 32];   //  8KB each
  const int L = xcd_swz(blockIdx.x, nwg);
  const int nt = L & 3, mt = L >> 2;           // N=512 -> 4 col tiles of 128
  const int tid = threadIdx.x, lane = tid & 63, wid = tid >> 6;
  const int wm = wid >> 1, wn = wid & 1;       // 2x2: 128 rows x 64 cols per wave
  const int lm = lane & 15, rch = lane >> 4;

  const unsigned short* Ag = A1 + (size_t)(mt * 256) * 512;
  const unsigned short* A2g = SPLITA ? A2 + (size_t)(mt * 256) * 128 : nullptr;
  const unsigned short* Wg = WT + (size_t)(nt * 128) * K;

  f32x4 acc[8][4] = {};

  auto stage = [&](int buf, int kb) {
#pragma unroll
    for (int i2 = 0; i2 < 4; ++i2) {           // A: 256 rows x 4 chunks
      int f = i2 * 256 + tid;
      int row = f >> 2;
      int sc = ((f & 3) ^ ((row >> 1) & 3)) << 3;
      if constexpr (SPLITA) {
        if (kb < 512) gll16(Ag + (size_t)row * 512 + kb + sc, &As[buf][f * 8]);
        else          gll16(A2g + (size_t)row * 128 + (kb - 512) + sc, &As[buf][f * 8]);
      } else {
        gll16(Ag + (size_t)row * 512 + kb + sc, &As[buf][f * 8]);
      }
    }
#pragma unroll
    for (int i2 = 0; i2 < 2; ++i2) {           // W: 128 rows x 4 chunks
      int f = i2 * 256 + tid;
      int row = f >> 2;
      int sc = ((f & 3) ^ ((row >> 1) & 3)) << 3;
      gll16(Wg + (size_t)row * K + kb + sc, &Ws[buf][f * 8]);
    }
  };

  stage(0, 0);

  for (int kt = 0; kt < KT; ++kt) {
    const int cur = kt & 1;
    __syncthreads();  // buf[cur] staged; buf[cur^1] readers done
    if (kt + 1 < KT) stage(cur ^ 1, (kt + 1) * 32);

    short8 af[8], wf[4];
#pragma unroll
    for (int mi = 0; mi < 8; ++mi) {
      int rw = wm * 128 + mi * 16 + lm;
      af[mi] = *reinterpret_cast<const short8*>(
          &As[cur][rw * 32 + ((rch ^ ((rw >> 1) & 3)) << 3)]);
    }
#pragma unroll
    for (int ni = 0; ni < 4; ++ni) {
      int rw = wn * 64 + ni * 16 + lm;
      wf[ni] = *reinterpret_cast<const short8*>(
          &Ws[cur][rw * 32 + ((rch ^ ((rw >> 1) & 3)) << 3)]);
    }
    __builtin_amdgcn_s_setprio(1);
#pragma unroll
    for (int mi = 0; mi < 8; ++mi)
#pragma unroll
      for (int ni = 0; ni < 4; ++ni)
        acc[mi][ni] = __builtin_amdgcn_mfma_f32_16x16x32_bf16(wf[ni], af[mi], acc[mi][ni], 0, 0, 0);
    __builtin_amdgcn_s_setprio(0);
  }

  // Transposed D layout: thread holds C[m][n0..n0+3]
  //   m  = mt*256 + wm*128 + mi*16 + (lane&15)
  //   n0 = nt*128 + wn*64  + ni*16 + (lane>>4)*4
#pragma unroll
  for (int mi = 0; mi < 8; ++mi) {
    const int m = mt * 256 + wm * 128 + mi * 16 + lm;
    float part = 0.f;
#pragma unroll
    for (int ni = 0; ni < 4; ++ni) {
      const int n0 = nt * 128 + wn * 64 + ni * 16 + (rch << 2);
      const f32x4 bb = *reinterpret_cast<const f32x4*>(bias + n0);
      f32x4 v = acc[mi][ni];
      if constexpr (!FUSE) {
        union { unsigned short u[4]; uint2 qv; } o;
#pragma unroll
        for (int rr = 0; rr < 4; ++rr) o.u[rr] = f2bf(softplus_fast(v[rr] + bb[rr]));
        *reinterpret_cast<uint2*>(C + (size_t)m * 512 + n0) = o.qv;
      } else {
        const f32x4 wv = *reinterpret_cast<const f32x4*>(W2 + n0);
#pragma unroll
        for (int rr = 0; rr < 4; ++rr) part += softplus_fast(v[rr] + bb[rr]) * wv[rr];
      }
    }
    if constexpr (FUSE) {
      part += __shfl_xor(part, 16);
      part += __shfl_xor(part, 32);
      if (lane < 16) atomicAdd(logits + m, part);
    }
  }
}

// ---------------------------------------------------------------------------
// Per-segment softmax: one block per segment; batch sorted -> binary search.
// (b2 omitted: softmax is shift-invariant.)
// ---------------------------------------------------------------------------
__global__ __launch_bounds__(256) void segsoftmax(const float* __restrict__ logits,
                                                  const int* __restrict__ batch,
                                                  float* __restrict__ out, int N) {
  const int g = blockIdx.x;
  const int tid = threadIdx.x;
  int lo = 0, hi = N;
  while (lo < hi) { int mid = (lo + hi) >> 1; if (batch[mid] < g) lo = mid + 1; else hi = mid; }
  const int beg = lo;
  hi = N;
  while (lo < hi) { int mid = (lo + hi) >> 1; if (batch[mid] < g + 1) lo = mid + 1; else hi = mid; }
  const int end = lo;
  if (beg >= end) return;

  __shared__ float sh[4];
  float m = -INFINITY;
  for (int i = beg + tid; i < end; i += 256) m = fmaxf(m, logits[i]);
#pragma unroll
  for (int o = 32; o; o >>= 1) m = fmaxf(m, __shfl_down(m, o));
  if ((tid & 63) == 0) sh[tid >> 6] = m;
  __syncthreads();
  m = fmaxf(fmaxf(sh[0], sh[1]), fmaxf(sh[2], sh[3]));
  __syncthreads();

  float s = 0.f;
  for (int i = beg + tid; i < end; i += 256) s += expf(logits[i] - m);
#pragma unroll
  for (int o = 32; o; o >>= 1) s += __shfl_down(s, o);
  if ((tid & 63) == 0) sh[tid >> 6] = s;
  __syncthreads();
  s = sh[0] + sh[1] + sh[2] + sh[3];

  const float inv = 1.f / (s + 1e-16f);
  for (int i = beg + tid; i < end; i += 256) out[i] = expf(logits[i] - m) * inv;
}

// ---------------------------------------------------------------------------
extern "C" void kernel_launch(void* const* d_in, const int* in_sizes, int n_in,
                              void* d_out, int out_size, void* d_ws, size_t ws_size,
                              hipStream_t stream) {
  const float* x = (const float*)d_in[0];
  const int* batch = (const int*)d_in[1];
  const float* gx = (const float*)d_in[2];
  const float* W0 = (const float*)d_in[3];
  const float* b0 = (const float*)d_in[4];
  const float* W1 = (const float*)d_in[5];
  const float* b1 = (const float*)d_in[6];
  const float* W2 = (const float*)d_in[7];
  float* out = (float*)d_out;

  const int N = in_sizes[1];                 // 100000
  const int Mp = ((N + 255) / 256) * 256;    // 100096 (=256*391)
  const int nwg = (Mp / 256) * 4;            // 1564 blocks per GEMM

  auto align256 = [](size_t v) { return (v + 255) & ~(size_t)255; };
  char* ws = (char*)d_ws;
  size_t off = 0;
  unsigned short* X16 = (unsigned short*)(ws + off); off = align256(off + (size_t)Mp * 512 * 2);
  unsigned short* G16 = (unsigned short*)(ws + off); off = align256(off + (size_t)Mp * 128 * 2);
  unsigned short* W0T = (unsigned short*)(ws + off); off = align256(off + (size_t)512 * 640 * 2);
  unsigned short* W1T = (unsigned short*)(ws + off); off = align256(off + (size_t)512 * 512 * 2);
  unsigned short* H0 = (unsigned short*)(ws + off);  off = align256(off + (size_t)Mp * 512 * 2);
  float* logits = (float*)(ws + off);                off = align256(off + (size_t)Mp * 4);
  (void)ws_size; (void)n_in; (void)out_size;

  const int prep_elems = 512 * 640 + 512 * 512 + Mp;
  prep<<<(prep_elems + 255) / 256, 256, 0, stream>>>(W0, W1, W0T, W1T, logits, Mp);
  pack<<<(Mp * 80 + 255) / 256, 256, 0, stream>>>(x, gx, X16, G16, N, Mp);

  gemm_bf16<640, true, false><<<nwg, 256, 0, stream>>>(X16, G16, W0T, b0, H0, nullptr, nullptr, nwg);
  gemm_bf16<512, false, true><<<nwg, 256, 0, stream>>>(H0, nullptr, W1T, b1, nullptr, W2, logits, nwg);

  segsoftmax<<<NSEG, 256, 0, stream>>>(logits, batch, out, N);
}

// Round 8
// 273.155 us; speedup vs baseline: 1.1990x; 1.1990x over previous
//
#include <hip/hip_runtime.h>
#include <hip/hip_bf16.h>
#include <math.h>

// ---------------------------------------------------------------------------
// GATGNN global attention:  softmax_seg( MLP([x|glbl]) )  on MI355X (gfx950)
// R8: gemm0 stages A directly from fp32 x via global_load_lds (fp32 LDS tile,
//     cvt->bf16 after ds_read). Kills the 105us pack round-trip for x.
//     gx pre-packed to fp32 G32[Mp,128]. gemm1 = proven R6 structure.
// ---------------------------------------------------------------------------

#define NSEG 1024

typedef __attribute__((ext_vector_type(8))) short short8;
typedef __attribute__((ext_vector_type(4))) float f32x4;

__device__ __forceinline__ unsigned short f2bf(float f) {
  __hip_bfloat16 h = __float2bfloat16(f);
  return *reinterpret_cast<unsigned short*>(&h);
}
__device__ __forceinline__ float softplus_fast(float z) {
  float t = __expf(-fabsf(z));
  return fmaxf(z, 0.f) + __logf(1.f + t);
}
__device__ __forceinline__ void gll16(const void* g, void* l) {
  __builtin_amdgcn_global_load_lds(
      (const __attribute__((address_space(1))) void*)g,
      (__attribute__((address_space(3))) void*)l, 16, 0, 0);
}
// m204 bijective XCD-chunked swizzle: each XCD owns a contiguous L-range.
__device__ __forceinline__ int xcd_swz(int bid, int nwg) {
  int q = nwg >> 3, r = nwg & 7, x = bid & 7, i = bid >> 3;
  return (x < r ? x * (q + 1) : r * (q + 1) + (x - r) * q) + i;
}

// ---------------------------------------------------------------------------
// prep: W0 [620,512] -> W0T bf16 [512,640] (K-pad 0), W1 -> W1T [512,512],
//       zero logits.
// ---------------------------------------------------------------------------
__global__ __launch_bounds__(256) void prep(const float* __restrict__ W0,
                                            const float* __restrict__ W1,
                                            unsigned short* __restrict__ W0T,
                                            unsigned short* __restrict__ W1T,
                                            float* __restrict__ logits, int Mp) {
  int t = blockIdx.x * 256 + threadIdx.x;
  if (t < 512 * 640) {
    int n = t / 640, k = t % 640;
    W0T[t] = f2bf(k < 620 ? W0[(size_t)k * 512 + n] : 0.f);
    return;
  }
  t -= 512 * 640;
  if (t < 512 * 512) {
    int n = t / 512, k = t % 512;
    W1T[t] = f2bf(W1[(size_t)k * 512 + n]);
    return;
  }
  t -= 512 * 512;
  if (t < Mp) logits[t] = 0.f;
}

// ---------------------------------------------------------------------------
// pack_g: gx [N,108] f32 -> G32 [Mp,128] f32 (cols 108..127 and pad rows = 0)
// One thread per 4-float granule (16B store).
// ---------------------------------------------------------------------------
__global__ __launch_bounds__(256) void pack_g(const float* __restrict__ gx,
                                              float* __restrict__ G32,
                                              int N, int Mp) {
  int t = blockIdx.x * 256 + threadIdx.x;
  if (t >= Mp * 32) return;
  int row = t >> 5, c = (t & 31) << 2;
  float4 v;
  v.x = (row < N && c + 0 < 108) ? gx[(size_t)row * 108 + c + 0] : 0.f;
  v.y = (row < N && c + 1 < 108) ? gx[(size_t)row * 108 + c + 1] : 0.f;
  v.z = (row < N && c + 2 < 108) ? gx[(size_t)row * 108 + c + 2] : 0.f;
  v.w = (row < N && c + 3 < 108) ? gx[(size_t)row * 108 + c + 3] : 0.f;
  *reinterpret_cast<float4*>(G32 + (size_t)row * 128 + c) = v;
}

// ---------------------------------------------------------------------------
// GEMM0: H0 = bf16(softplus([x|G32] * W0T^T + b0)).  128x128 tile, BK=32,
// 4 waves (2x2), 64x64/wave, mfma(w,a) swapped. A staged as FP32 via
// global_load_lds (granule swizzle s^(r&7), 16B granules), converted to bf16
// in registers after ds_read_b128. W staged bf16 (chunk swizzle c^((r>>1)&3)).
// LDS 48KB -> 3 blocks/CU. OOB rows clamp to N-1 (pad output garbage, unread).
// ---------------------------------------------------------------------------
__global__ __launch_bounds__(256, 3) void gemm0(const float* __restrict__ x,
                                                const float* __restrict__ G32,
                                                const unsigned short* __restrict__ W0T,
                                                const float* __restrict__ b0,
                                                unsigned short* __restrict__ H0,
                                                int N, int nwg) {
  constexpr int K = 640, KT = 20;
  __shared__ float Asf[2][128 * 32];            // 16KB per buffer (fp32)
  __shared__ unsigned short Ws[2][128 * 32];    //  8KB per buffer (bf16)
  const int L = xcd_swz(blockIdx.x, nwg);
  const int nt = L & 3, mt = L >> 2;
  const int tid = threadIdx.x, lane = tid & 63, wid = tid >> 6;
  const int wm = wid >> 1, wn = wid & 1, lm = lane & 15, rch = lane >> 4;

  const unsigned short* Wg = W0T + (size_t)(nt * 128) * K;

  f32x4 acc[4][4] = {};

  // A: 128 rows x 8 granules(4 floats); thread f -> row f>>3, slot f&7.
  // LDS slot s holds global granule s^(r&7)  (inverse-swz source, linear dest)
  auto stageA = [&](int buf, int kb) {
#pragma unroll
    for (int i2 = 0; i2 < 4; ++i2) {
      int f = i2 * 256 + tid;
      int r = f >> 3, s = f & 7;
      int g4 = (s ^ (r & 7)) << 2;              // float offset within 32-wide slice
      const float* src;
      if (kb < 512) {
        int rg = mt * 128 + r; if (rg >= N) rg = N - 1;   // clamp (pad rows unread)
        src = x + (size_t)rg * 512 + kb + g4;
      } else {
        int rg = mt * 128 + r;                  // G32 has Mp padded rows
        src = G32 + (size_t)rg * 128 + (kb - 512) + g4;
      }
      gll16(src, &Asf[buf][r * 32 + s * 4]);
    }
  };
  auto stageW = [&](int buf, int kb) {
#pragma unroll
    for (int i2 = 0; i2 < 2; ++i2) {
      int f = i2 * 256 + tid;
      int row = f >> 2;
      int sc = ((f & 3) ^ ((row >> 1) & 3)) << 3;
      gll16(Wg + (size_t)row * K + kb + sc, &Ws[buf][f * 8]);
    }
  };

  stageA(0, 0);
  stageW(0, 0);

  for (int kt = 0; kt < KT; ++kt) {
    const int cur = kt & 1;
    __syncthreads();  // buf[cur] staged (vmcnt drained); buf[cur^1] readers done
    if (kt + 1 < KT) { stageA(cur ^ 1, (kt + 1) * 32); stageW(cur ^ 1, (kt + 1) * 32); }

    short8 af[4], wf[4];
#pragma unroll
    for (int mi = 0; mi < 4; ++mi) {
      int rw = wm * 64 + mi * 16 + lm;
      const float* base = &Asf[cur][rw * 32];
      f32x4 lo = *reinterpret_cast<const f32x4*>(base + ((((2 * rch) ^ (rw & 7)) << 2)));
      f32x4 hi = *reinterpret_cast<const f32x4*>(base + ((((2 * rch + 1) ^ (rw & 7)) << 2)));
      union { unsigned short u[8]; short8 s8; } cv;
#pragma unroll
      for (int j = 0; j < 4; ++j) { cv.u[j] = f2bf(lo[j]); cv.u[4 + j] = f2bf(hi[j]); }
      af[mi] = cv.s8;
    }
#pragma unroll
    for (int ni = 0; ni < 4; ++ni) {
      int rw = wn * 64 + ni * 16 + lm;
      wf[ni] = *reinterpret_cast<const short8*>(
          &Ws[cur][rw * 32 + ((rch ^ ((rw >> 1) & 3)) << 3)]);
    }
    __builtin_amdgcn_s_setprio(1);
#pragma unroll
    for (int mi = 0; mi < 4; ++mi)
#pragma unroll
      for (int ni = 0; ni < 4; ++ni)
        acc[mi][ni] = __builtin_amdgcn_mfma_f32_16x16x32_bf16(wf[ni], af[mi], acc[mi][ni], 0, 0, 0);
    __builtin_amdgcn_s_setprio(0);
  }

  // epilogue: thread holds C[m][n0..n0+3]
#pragma unroll
  for (int mi = 0; mi < 4; ++mi) {
    const int m = mt * 128 + wm * 64 + mi * 16 + lm;
#pragma unroll
    for (int ni = 0; ni < 4; ++ni) {
      const int n0 = nt * 128 + wn * 64 + ni * 16 + (rch << 2);
      const f32x4 bb = *reinterpret_cast<const f32x4*>(b0 + n0);
      f32x4 v = acc[mi][ni];
      union { unsigned short u[4]; uint2 qv; } o;
#pragma unroll
      for (int rr = 0; rr < 4; ++rr) o.u[rr] = f2bf(softplus_fast(v[rr] + bb[rr]));
      *reinterpret_cast<uint2*>(H0 + (size_t)m * 512 + n0) = o.qv;
    }
  }
}

// ---------------------------------------------------------------------------
// GEMM1 (+logit fusion): logits[m] += sum_n softplus(H0*W1T^T + b1)[m][n]*W2[n]
// R6-proven: 128x128, BK=32, both panels bf16 via global_load_lds, 32KB LDS,
// 4 blocks/CU.
// ---------------------------------------------------------------------------
__global__ __launch_bounds__(256, 4) void gemm1(const unsigned short* __restrict__ H0,
                                                const unsigned short* __restrict__ W1T,
                                                const float* __restrict__ b1,
                                                const float* __restrict__ W2,
                                                float* __restrict__ logits, int nwg) {
  constexpr int K = 512, KT = 16;
  __shared__ unsigned short As[2][128 * 32];
  __shared__ unsigned short Ws[2][128 * 32];
  const int L = xcd_swz(blockIdx.x, nwg);
  const int nt = L & 3, mt = L >> 2;
  const int tid = threadIdx.x, lane = tid & 63, wid = tid >> 6;
  const int wm = wid >> 1, wn = wid & 1, lm = lane & 15, rch = lane >> 4;

  const unsigned short* Ag = H0 + (size_t)(mt * 128) * K;
  const unsigned short* Wg = W1T + (size_t)(nt * 128) * K;

  f32x4 acc[4][4] = {};

  auto stage = [&](int buf, int kb) {
#pragma unroll
    for (int i2 = 0; i2 < 2; ++i2) {
      int f = i2 * 256 + tid;
      int row = f >> 2;
      int sc = ((f & 3) ^ ((row >> 1) & 3)) << 3;
      gll16(Ag + (size_t)row * K + kb + sc, &As[buf][f * 8]);
      gll16(Wg + (size_t)row * K + kb + sc, &Ws[buf][f * 8]);
    }
  };

  stage(0, 0);

  for (int kt = 0; kt < KT; ++kt) {
    const int cur = kt & 1;
    __syncthreads();
    if (kt + 1 < KT) stage(cur ^ 1, (kt + 1) * 32);

    short8 af[4], wf[4];
#pragma unroll
    for (int mi = 0; mi < 4; ++mi) {
      int rw = wm * 64 + mi * 16 + lm;
      af[mi] = *reinterpret_cast<const short8*>(
          &As[cur][rw * 32 + ((rch ^ ((rw >> 1) & 3)) << 3)]);
    }
#pragma unroll
    for (int ni = 0; ni < 4; ++ni) {
      int rw = wn * 64 + ni * 16 + lm;
      wf[ni] = *reinterpret_cast<const short8*>(
          &Ws[cur][rw * 32 + ((rch ^ ((rw >> 1) & 3)) << 3)]);
    }
    __builtin_amdgcn_s_setprio(1);
#pragma unroll
    for (int mi = 0; mi < 4; ++mi)
#pragma unroll
      for (int ni = 0; ni < 4; ++ni)
        acc[mi][ni] = __builtin_amdgcn_mfma_f32_16x16x32_bf16(wf[ni], af[mi], acc[mi][ni], 0, 0, 0);
    __builtin_amdgcn_s_setprio(0);
  }

#pragma unroll
  for (int mi = 0; mi < 4; ++mi) {
    const int m = mt * 128 + wm * 64 + mi * 16 + lm;
    float part = 0.f;
#pragma unroll
    for (int ni = 0; ni < 4; ++ni) {
      const int n0 = nt * 128 + wn * 64 + ni * 16 + (rch << 2);
      const f32x4 bb = *reinterpret_cast<const f32x4*>(b1 + n0);
      const f32x4 wv = *reinterpret_cast<const f32x4*>(W2 + n0);
      f32x4 v = acc[mi][ni];
#pragma unroll
      for (int rr = 0; rr < 4; ++rr) part += softplus_fast(v[rr] + bb[rr]) * wv[rr];
    }
    part += __shfl_xor(part, 16);
    part += __shfl_xor(part, 32);
    if (lane < 16) atomicAdd(logits + m, part);
  }
}

// ---------------------------------------------------------------------------
// Per-segment softmax: one block per segment; batch sorted -> binary search.
// (b2 omitted: softmax is shift-invariant.)
// ---------------------------------------------------------------------------
__global__ __launch_bounds__(256) void segsoftmax(const float* __restrict__ logits,
                                                  const int* __restrict__ batch,
                                                  float* __restrict__ out, int N) {
  const int g = blockIdx.x;
  const int tid = threadIdx.x;
  int lo = 0, hi = N;
  while (lo < hi) { int mid = (lo + hi) >> 1; if (batch[mid] < g) lo = mid + 1; else hi = mid; }
  const int beg = lo;
  hi = N;
  while (lo < hi) { int mid = (lo + hi) >> 1; if (batch[mid] < g + 1) lo = mid + 1; else hi = mid; }
  const int end = lo;
  if (beg >= end) return;

  __shared__ float sh[4];
  float m = -INFINITY;
  for (int i = beg + tid; i < end; i += 256) m = fmaxf(m, logits[i]);
#pragma unroll
  for (int o = 32; o; o >>= 1) m = fmaxf(m, __shfl_down(m, o));
  if ((tid & 63) == 0) sh[tid >> 6] = m;
  __syncthreads();
  m = fmaxf(fmaxf(sh[0], sh[1]), fmaxf(sh[2], sh[3]));
  __syncthreads();

  float s = 0.f;
  for (int i = beg + tid; i < end; i += 256) s += expf(logits[i] - m);
#pragma unroll
  for (int o = 32; o; o >>= 1) s += __shfl_down(s, o);
  if ((tid & 63) == 0) sh[tid >> 6] = s;
  __syncthreads();
  s = sh[0] + sh[1] + sh[2] + sh[3];

  const float inv = 1.f / (s + 1e-16f);
  for (int i = beg + tid; i < end; i += 256) out[i] = expf(logits[i] - m) * inv;
}

// ---------------------------------------------------------------------------
extern "C" void kernel_launch(void* const* d_in, const int* in_sizes, int n_in,
                              void* d_out, int out_size, void* d_ws, size_t ws_size,
                              hipStream_t stream) {
  const float* x = (const float*)d_in[0];
  const int* batch = (const int*)d_in[1];
  const float* gx = (const float*)d_in[2];
  const float* W0 = (const float*)d_in[3];
  const float* b0 = (const float*)d_in[4];
  const float* W1 = (const float*)d_in[5];
  const float* b1 = (const float*)d_in[6];
  const float* W2 = (const float*)d_in[7];
  float* out = (float*)d_out;

  const int N = in_sizes[1];                 // 100000
  const int Mp = ((N + 127) / 128) * 128;    // 100096
  const int nwg = (Mp / 128) * 4;            // 3128 blocks per GEMM (3128%8==0)

  auto align256 = [](size_t v) { return (v + 255) & ~(size_t)255; };
  char* ws = (char*)d_ws;
  size_t off = 0;
  float* G32 = (float*)(ws + off);                   off = align256(off + (size_t)Mp * 128 * 4);
  unsigned short* W0T = (unsigned short*)(ws + off); off = align256(off + (size_t)512 * 640 * 2);
  unsigned short* W1T = (unsigned short*)(ws + off); off = align256(off + (size_t)512 * 512 * 2);
  unsigned short* H0 = (unsigned short*)(ws + off);  off = align256(off + (size_t)Mp * 512 * 2);
  float* logits = (float*)(ws + off);                off = align256(off + (size_t)Mp * 4);
  (void)ws_size; (void)n_in; (void)out_size;

  const int prep_elems = 512 * 640 + 512 * 512 + Mp;
  prep<<<(prep_elems + 255) / 256, 256, 0, stream>>>(W0, W1, W0T, W1T, logits, Mp);
  pack_g<<<(Mp * 32 + 255) / 256, 256, 0, stream>>>(gx, G32, N, Mp);

  gemm0<<<nwg, 256, 0, stream>>>(x, G32, W0T, b0, H0, N, nwg);
  gemm1<<<nwg, 256, 0, stream>>>(H0, W1T, b1, W2, logits, nwg);

  segsoftmax<<<NSEG, 256, 0, stream>>>(logits, batch, out, N);
}